// Round 8
// baseline (272.722 us; speedup 1.0000x reference)
//
#include <hip/hip_runtime.h>
#include <math.h>

// softIoULoss: out = 1 - (I + 1) / (M + (nc+1)*S - I + 1)
//   I = sum(sigmoid(0.5 - |x-t|) * matched)
//   M = sum(matched),  S = sum(sigmoid(0.5 - |x-t|))
//   matched = (t == floor(t)) && (t >= 0) && (t <= nc)
//
// R7 post-mortem: depth 4->8 gained 7 us at constant in-flight/CU -> gains come
// from amortizing issue/drain epochs, not raw MLP. R8: PAIRS=16 (32 NT loads
// in flight/thread, ~200 VGPR, 2-3 waves/SIMD, same ~256 KB in-flight/CU,
// half the wave count). If flat/regress: R7 kernel is the HBM-floor keeper.

#define BLOCK 256
#define PAIRS 16   // float4-pairs per thread per straight-line round
#define MAXGRID 16384

typedef float f4_t __attribute__((ext_vector_type(4)));

__device__ __forceinline__ void accum4(f4_t xv, f4_t tv, float ncf,
                                       float& s_inter, float& s_match, float& s_sig) {
#pragma unroll
    for (int j = 0; j < 4; ++j) {
        float tt = tv[j];
        float z  = 0.5f - fabsf(xv[j] - tt);
        float sg = __builtin_amdgcn_rcpf(1.0f + __expf(-z));
        float m  = (tt == floorf(tt) && tt >= 0.f && tt <= ncf) ? 1.f : 0.f;
        s_sig   += sg;
        s_match += m;
        s_inter += sg * m;
    }
}

__global__ __launch_bounds__(BLOCK) void soft_iou_partial(
    const float* __restrict__ x,
    const float* __restrict__ t,
    const int* __restrict__ ncls_p,
    float* __restrict__ pI,     // [gridDim.x]
    float* __restrict__ pM,     // [gridDim.x]
    float* __restrict__ pS,     // [gridDim.x]
    int n)
{
    const int tid = threadIdx.x;
    const long long nthreads = (long long)gridDim.x * BLOCK;
    const long long gtid     = (long long)blockIdx.x * BLOCK + tid;

    const float ncf = (float)(*ncls_p);

    float s_inter = 0.f, s_match = 0.f, s_sig = 0.f;

    const long long nvec = (long long)n >> 2;   // float4 count
    const f4_t* __restrict__ x4 = (const f4_t*)x;
    const f4_t* __restrict__ t4 = (const f4_t*)t;

    long long i = gtid;
    // straight-line round: 2*PAIRS independent NT dwordx4 loads, interleaved
    // x/t so accum-k only waits on the two oldest outstanding loads.
    for (; i + (PAIRS - 1) * nthreads < nvec; i += (long long)PAIRS * nthreads) {
        f4_t xv[PAIRS], tv[PAIRS];
#pragma unroll
        for (int k = 0; k < PAIRS; ++k) {
            xv[k] = __builtin_nontemporal_load(&x4[i + (long long)k * nthreads]);
            tv[k] = __builtin_nontemporal_load(&t4[i + (long long)k * nthreads]);
        }
        __builtin_amdgcn_sched_barrier(0);
#pragma unroll
        for (int k = 0; k < PAIRS; ++k)
            accum4(xv[k], tv[k], ncf, s_inter, s_match, s_sig);
    }
    // remaining full float4s
    for (; i < nvec; i += nthreads) {
        accum4(x4[i], t4[i], ncf, s_inter, s_match, s_sig);
    }
    // scalar tail (n % 4)
    for (long long k = (nvec << 2) + gtid; k < n; k += nthreads) {
        float tt = t[k];
        float z  = 0.5f - fabsf(x[k] - tt);
        float sg = __builtin_amdgcn_rcpf(1.0f + __expf(-z));
        float m  = (tt == floorf(tt) && tt >= 0.f && tt <= ncf) ? 1.f : 0.f;
        s_sig += sg; s_match += m; s_inter += sg * m;
    }

    // wave (64-lane) reduction
#pragma unroll
    for (int off = 32; off > 0; off >>= 1) {
        s_inter += __shfl_down(s_inter, off, 64);
        s_match += __shfl_down(s_match, off, 64);
        s_sig   += __shfl_down(s_sig,   off, 64);
    }

    __shared__ float sh[3][4];   // 4 waves for block=256
    const int wid = tid >> 6;
    const int lid = tid & 63;
    if (lid == 0) { sh[0][wid] = s_inter; sh[1][wid] = s_match; sh[2][wid] = s_sig; }
    __syncthreads();

    if (tid == 0) {
        pI[blockIdx.x] = sh[0][0] + sh[0][1] + sh[0][2] + sh[0][3];
        pM[blockIdx.x] = sh[1][0] + sh[1][1] + sh[1][2] + sh[1][3];
        pS[blockIdx.x] = sh[2][0] + sh[2][1] + sh[2][2] + sh[2][3];
    }
}

__global__ __launch_bounds__(256) void soft_iou_final(
    const float* __restrict__ pI,
    const float* __restrict__ pM,
    const float* __restrict__ pS,
    const int* __restrict__ ncls_p,
    float* __restrict__ out,
    int g)
{
    const int tid = threadIdx.x;
    const f4_t* pI4 = (const f4_t*)pI;
    const f4_t* pM4 = (const f4_t*)pM;
    const f4_t* pS4 = (const f4_t*)pS;
    const int g4 = g >> 2;
    float si = 0.f, sm = 0.f, ss = 0.f;
    for (int i = tid; i < g4; i += 256) {
        f4_t a = pI4[i], b = pM4[i], c = pS4[i];
        si += a[0] + a[1] + a[2] + a[3];
        sm += b[0] + b[1] + b[2] + b[3];
        ss += c[0] + c[1] + c[2] + c[3];
    }
    // tail if g not multiple of 4
    for (int i = (g4 << 2) + tid; i < g; i += 256) {
        si += pI[i]; sm += pM[i]; ss += pS[i];
    }
#pragma unroll
    for (int off = 32; off > 0; off >>= 1) {
        si += __shfl_down(si, off, 64);
        sm += __shfl_down(sm, off, 64);
        ss += __shfl_down(ss, off, 64);
    }
    __shared__ float sh[3][4];
    const int wid = tid >> 6;
    const int lid = tid & 63;
    if (lid == 0) { sh[0][wid] = si; sh[1][wid] = sm; sh[2][wid] = ss; }
    __syncthreads();
    if (tid == 0) {
        float I = sh[0][0] + sh[0][1] + sh[0][2] + sh[0][3];
        float M = sh[1][0] + sh[1][1] + sh[1][2] + sh[1][3];
        float S = sh[2][0] + sh[2][1] + sh[2][2] + sh[2][3];
        float ncf = (float)(*ncls_p);
        float uni = M + (ncf + 1.f) * S - I;
        out[0] = 1.f - (I + 1.f) / (uni + 1.f);
    }
}

extern "C" void kernel_launch(void* const* d_in, const int* in_sizes, int n_in,
                              void* d_out, int out_size, void* d_ws, size_t ws_size,
                              hipStream_t stream) {
    const float* x  = (const float*)d_in[0];
    const float* t  = (const float*)d_in[1];
    const int*   nc = (const int*)d_in[2];
    float* out = (float*)d_out;
    const int n = in_sizes[0];

    // grid sized so most threads do exactly one straight-line round
    long long nvec = (long long)n >> 2;
    long long threads_needed = (nvec + PAIRS - 1) / PAIRS;
    int grid = (int)((threads_needed + BLOCK - 1) / BLOCK);
    if (grid < 1) grid = 1;
    if (grid > MAXGRID) grid = MAXGRID;

    float* pI = (float*)d_ws;
    float* pM = pI + MAXGRID;
    float* pS = pM + MAXGRID;

    soft_iou_partial<<<grid, BLOCK, 0, stream>>>(x, t, nc, pI, pM, pS, n);
    soft_iou_final<<<1, 256, 0, stream>>>(pI, pM, pS, nc, out, grid);
}

// Round 9
// 259.004 us; speedup vs baseline: 1.0530x; 1.0530x over previous
//
#include <hip/hip_runtime.h>
#include <math.h>

// softIoULoss: out = 1 - (I + 1) / (M + (nc+1)*S - I + 1)
//   I = sum(sigmoid(0.5 - |x-t|) * matched)
//   M = sum(matched),  S = sum(sigmoid(0.5 - |x-t|))
//   matched = (t == floor(t)) && (t >= 0) && (t <= nc)
//
// R8 post-mortem: PAIRS=16 (~200 VGPR, 2 waves/SIMD) regressed 257->273;
// depth-response peaked at PAIRS=8. R9 = revert to the R7 keeper:
// PAIRS=8, interleaved x/t NT dwordx4 straight-line rounds, sched_barrier(0),
// atomic-free two-kernel reduction, vectorized finalize.
// Remaining bench time = ~170 us harness reset + ~43-55 us mandatory 268 MB
// HBM read (the harness's 512 MB ws poison evicts L3 each iter).

#define BLOCK 256
#define PAIRS 8    // float4-pairs per thread per straight-line round (measured optimum)
#define MAXGRID 16384

typedef float f4_t __attribute__((ext_vector_type(4)));

__device__ __forceinline__ void accum4(f4_t xv, f4_t tv, float ncf,
                                       float& s_inter, float& s_match, float& s_sig) {
#pragma unroll
    for (int j = 0; j < 4; ++j) {
        float tt = tv[j];
        float z  = 0.5f - fabsf(xv[j] - tt);
        float sg = __builtin_amdgcn_rcpf(1.0f + __expf(-z));
        float m  = (tt == floorf(tt) && tt >= 0.f && tt <= ncf) ? 1.f : 0.f;
        s_sig   += sg;
        s_match += m;
        s_inter += sg * m;
    }
}

__global__ __launch_bounds__(BLOCK) void soft_iou_partial(
    const float* __restrict__ x,
    const float* __restrict__ t,
    const int* __restrict__ ncls_p,
    float* __restrict__ pI,     // [gridDim.x]
    float* __restrict__ pM,     // [gridDim.x]
    float* __restrict__ pS,     // [gridDim.x]
    int n)
{
    const int tid = threadIdx.x;
    const long long nthreads = (long long)gridDim.x * BLOCK;
    const long long gtid     = (long long)blockIdx.x * BLOCK + tid;

    const float ncf = (float)(*ncls_p);

    float s_inter = 0.f, s_match = 0.f, s_sig = 0.f;

    const long long nvec = (long long)n >> 2;   // float4 count
    const f4_t* __restrict__ x4 = (const f4_t*)x;
    const f4_t* __restrict__ t4 = (const f4_t*)t;

    long long i = gtid;
    // straight-line round: 2*PAIRS independent NT dwordx4 loads, interleaved
    // x/t so accum-k only waits on the two oldest outstanding loads.
    for (; i + (PAIRS - 1) * nthreads < nvec; i += (long long)PAIRS * nthreads) {
        f4_t xv[PAIRS], tv[PAIRS];
#pragma unroll
        for (int k = 0; k < PAIRS; ++k) {
            xv[k] = __builtin_nontemporal_load(&x4[i + (long long)k * nthreads]);
            tv[k] = __builtin_nontemporal_load(&t4[i + (long long)k * nthreads]);
        }
        __builtin_amdgcn_sched_barrier(0);
#pragma unroll
        for (int k = 0; k < PAIRS; ++k)
            accum4(xv[k], tv[k], ncf, s_inter, s_match, s_sig);
    }
    // remaining full float4s
    for (; i < nvec; i += nthreads) {
        accum4(x4[i], t4[i], ncf, s_inter, s_match, s_sig);
    }
    // scalar tail (n % 4)
    for (long long k = (nvec << 2) + gtid; k < n; k += nthreads) {
        float tt = t[k];
        float z  = 0.5f - fabsf(x[k] - tt);
        float sg = __builtin_amdgcn_rcpf(1.0f + __expf(-z));
        float m  = (tt == floorf(tt) && tt >= 0.f && tt <= ncf) ? 1.f : 0.f;
        s_sig += sg; s_match += m; s_inter += sg * m;
    }

    // wave (64-lane) reduction
#pragma unroll
    for (int off = 32; off > 0; off >>= 1) {
        s_inter += __shfl_down(s_inter, off, 64);
        s_match += __shfl_down(s_match, off, 64);
        s_sig   += __shfl_down(s_sig,   off, 64);
    }

    __shared__ float sh[3][4];   // 4 waves for block=256
    const int wid = tid >> 6;
    const int lid = tid & 63;
    if (lid == 0) { sh[0][wid] = s_inter; sh[1][wid] = s_match; sh[2][wid] = s_sig; }
    __syncthreads();

    if (tid == 0) {
        pI[blockIdx.x] = sh[0][0] + sh[0][1] + sh[0][2] + sh[0][3];
        pM[blockIdx.x] = sh[1][0] + sh[1][1] + sh[1][2] + sh[1][3];
        pS[blockIdx.x] = sh[2][0] + sh[2][1] + sh[2][2] + sh[2][3];
    }
}

__global__ __launch_bounds__(256) void soft_iou_final(
    const float* __restrict__ pI,
    const float* __restrict__ pM,
    const float* __restrict__ pS,
    const int* __restrict__ ncls_p,
    float* __restrict__ out,
    int g)
{
    const int tid = threadIdx.x;
    const f4_t* pI4 = (const f4_t*)pI;
    const f4_t* pM4 = (const f4_t*)pM;
    const f4_t* pS4 = (const f4_t*)pS;
    const int g4 = g >> 2;
    float si = 0.f, sm = 0.f, ss = 0.f;
    for (int i = tid; i < g4; i += 256) {
        f4_t a = pI4[i], b = pM4[i], c = pS4[i];
        si += a[0] + a[1] + a[2] + a[3];
        sm += b[0] + b[1] + b[2] + b[3];
        ss += c[0] + c[1] + c[2] + c[3];
    }
    // tail if g not multiple of 4
    for (int i = (g4 << 2) + tid; i < g; i += 256) {
        si += pI[i]; sm += pM[i]; ss += pS[i];
    }
#pragma unroll
    for (int off = 32; off > 0; off >>= 1) {
        si += __shfl_down(si, off, 64);
        sm += __shfl_down(sm, off, 64);
        ss += __shfl_down(ss, off, 64);
    }
    __shared__ float sh[3][4];
    const int wid = tid >> 6;
    const int lid = tid & 63;
    if (lid == 0) { sh[0][wid] = si; sh[1][wid] = sm; sh[2][wid] = ss; }
    __syncthreads();
    if (tid == 0) {
        float I = sh[0][0] + sh[0][1] + sh[0][2] + sh[0][3];
        float M = sh[1][0] + sh[1][1] + sh[1][2] + sh[1][3];
        float S = sh[2][0] + sh[2][1] + sh[2][2] + sh[2][3];
        float ncf = (float)(*ncls_p);
        float uni = M + (ncf + 1.f) * S - I;
        out[0] = 1.f - (I + 1.f) / (uni + 1.f);
    }
}

extern "C" void kernel_launch(void* const* d_in, const int* in_sizes, int n_in,
                              void* d_out, int out_size, void* d_ws, size_t ws_size,
                              hipStream_t stream) {
    const float* x  = (const float*)d_in[0];
    const float* t  = (const float*)d_in[1];
    const int*   nc = (const int*)d_in[2];
    float* out = (float*)d_out;
    const int n = in_sizes[0];

    // grid sized so most threads do exactly one straight-line round
    long long nvec = (long long)n >> 2;
    long long threads_needed = (nvec + PAIRS - 1) / PAIRS;
    int grid = (int)((threads_needed + BLOCK - 1) / BLOCK);
    if (grid < 1) grid = 1;
    if (grid > MAXGRID) grid = MAXGRID;

    float* pI = (float*)d_ws;
    float* pM = pI + MAXGRID;
    float* pS = pM + MAXGRID;

    soft_iou_partial<<<grid, BLOCK, 0, stream>>>(x, t, nc, pI, pM, pS, n);
    soft_iou_final<<<1, 256, 0, stream>>>(pI, pM, pS, nc, out, grid);
}